// Round 5
// baseline (546.709 us; speedup 1.0000x reference)
//
#include <hip/hip_runtime.h>
#include <hip/hip_bf16.h>

// Attention_89335319756981 — MI355X bf16-MFMA implementation, round 5.
// B=8, N=2880 (hw=576 + T=4 frames of 576), C=768, H=12, hd=64, TOPK=32.
//
// Round-5 changes:
//  - attn: scores stored as exp (monotonic -> search on exp keys), branchless
//    16-round 2-row-interleaved topk, permuted LDS rows (2-way conflicts max).
//  - gemm: 128x128 tile, BK=64, global_load_lds width-16 staging (m97-style).
//  - vtb transpose moved to a dedicated LDS-tiled kernel (coalesced).

using s16x8 = __attribute__((ext_vector_type(8))) short;
using f32x4 = __attribute__((ext_vector_type(4))) float;
typedef unsigned short u16;

#define MFMA_B16(A,B,C) __builtin_amdgcn_mfma_f32_16x16x32_bf16(A,B,C,0,0,0)

__device__ __forceinline__ u16 f2bf(float f) {
  unsigned u = __float_as_uint(f);
  u += 0x7FFFu + ((u >> 16) & 1u);          // RNE, no NaN inputs here
  return (u16)(u >> 16);
}
__device__ __forceinline__ float bf2f(u16 h) {
  return __uint_as_float(((unsigned)h) << 16);
}
__device__ __forceinline__ int lanes_below(unsigned long long m) {
  return __builtin_amdgcn_mbcnt_hi((unsigned)(m >> 32),
         __builtin_amdgcn_mbcnt_lo((unsigned)m, 0));
}
__device__ __forceinline__ void stage16(const u16* __restrict__ g, u16* l) {
  __builtin_amdgcn_global_load_lds(
      (const __attribute__((address_space(1))) unsigned int*)g,
      (__attribute__((address_space(3))) unsigned int*)l, 16, 0, 0);
}

// ---------------- f32 -> bf16 convert (4 elems/thread) ----------------
__global__ __launch_bounds__(256) void cvt_kernel(const float* __restrict__ src,
                                                  u16* __restrict__ dst, int n4) {
  int i = blockIdx.x * blockDim.x + threadIdx.x;
  if (i >= n4) return;
  float4 v = ((const float4*)src)[i];
  unsigned lo = (unsigned)f2bf(v.x) | ((unsigned)f2bf(v.y) << 16);
  unsigned hi = (unsigned)f2bf(v.z) | ((unsigned)f2bf(v.w) << 16);
  uint2 o; o.x = lo; o.y = hi;
  ((uint2*)dst)[i] = o;
}

// ---------------- passthrough copy: out[:,576:,:] = x[:,576:,:] ----------------
__global__ __launch_bounds__(256) void copy_tail_kernel(const float* __restrict__ x,
                                                        float* __restrict__ out) {
  int i = blockIdx.x * blockDim.x + threadIdx.x;   // float4 units
  int b = i / 442368;                              // 2304*768/4 per batch
  int off = i - b * 442368;
  size_t e = (size_t)b * 552960 + 110592 + off;    // (b*2880+576)*768/4 + off
  ((float4*)out)[e] = ((const float4*)x)[e];
}

// ---------------- V transpose: vtb[bh][d][key] = vbuf[bh][key][d] ----------------
__global__ __launch_bounds__(256) void transpose_v(const u16* __restrict__ vbuf,
                                                   u16* __restrict__ vtb) {
  __shared__ __align__(16) u16 s[64][72];
  const int r0 = blockIdx.x * 64;                 // key tile (0..44)
  const int bh = blockIdx.y;                      // 0..95
  const int t = threadIdx.x;
  const int kr = t >> 2, c0 = (t & 3) * 16;
  const u16* src = vbuf + (size_t)bh * 2880 * 64 + (size_t)(r0 + kr) * 64 + c0;
  *(int4*)&s[kr][c0]     = *(const int4*)&src[0];
  *(int4*)&s[kr][c0 + 8] = *(const int4*)&src[8];
  __syncthreads();
  const int d = t >> 2, k0 = (t & 3) * 16;
  u16 tmp[16];
  #pragma unroll
  for (int i = 0; i < 16; ++i) tmp[i] = s[k0 + i][d];
  u16* dst = vtb + ((size_t)bh * 64 + d) * 2880 + r0 + k0;
  *(int4*)&dst[0] = *(const int4*)&tmp[0];
  *(int4*)&dst[8] = *(const int4*)&tmp[8];
}

// ---------------- NT GEMM, 128x128 tile, BK=64, global_load_lds ----------------
// C[m][n] = sum_k A[m][k]*Bw[n][k]. 4 waves, each 64x64 quadrant (4x4 frags).
// MODE 0: QKV epilogue (scatter q/k/v). MODE 1: proj epilogue (f32+bias -> out).
template<int MODE>
__global__ __launch_bounds__(256) void gemm_nt(
    const u16* __restrict__ A, const u16* __restrict__ Bw,
    const float* __restrict__ bias,
    u16* __restrict__ qbuf, u16* __restrict__ kbuf,
    u16* __restrict__ vbuf, float* __restrict__ fout)
{
  __shared__ __align__(16) u16 sA[128 * 64];
  __shared__ __align__(16) u16 sB[128 * 64];
  const int n0 = blockIdx.x * 128;
  const int m0 = blockIdx.y * 128;
  if (MODE == 0 && n0 < 768) {
    // q columns only need rows rr<576; skip blocks fully in rr>=576
    const int s = m0 % 2880;
    if (s >= 576 && s + 128 <= 2880) return;
  }
  const int tid = threadIdx.x;
  const int w = tid >> 6, lane = tid & 63;
  const int l15 = lane & 15, rg = lane >> 4;
  const int ko = rg * 8;
  const int mq = (w >> 1) * 64, nq = (w & 1) * 64;
  const int trow = tid >> 3, tcol = (tid & 7) * 8;   // staging map (lane-linear LDS)

  f32x4 z = {0.f, 0.f, 0.f, 0.f};
  f32x4 acc[4][4];
  #pragma unroll
  for (int i = 0; i < 4; ++i)
    #pragma unroll
    for (int j = 0; j < 4; ++j) acc[i][j] = z;

  for (int k0 = 0; k0 < 768; k0 += 64) {
    __syncthreads();
    #pragma unroll
    for (int i = 0; i < 4; ++i) {
      stage16(&A[(size_t)(m0 + trow + i * 32) * 768 + k0 + tcol],
              &sA[(trow + i * 32) * 64 + tcol]);
      stage16(&Bw[(size_t)(n0 + trow + i * 32) * 768 + k0 + tcol],
              &sB[(trow + i * 32) * 64 + tcol]);
    }
    __syncthreads();
    #pragma unroll
    for (int kk = 0; kk < 2; ++kk) {
      const int ko2 = kk * 32 + ko;
      s16x8 af[4], bf[4];
      #pragma unroll
      for (int i = 0; i < 4; ++i) {
        af[i] = *(const s16x8*)&sA[(mq + i * 16 + l15) * 64 + ko2];
        bf[i] = *(const s16x8*)&sB[(nq + i * 16 + l15) * 64 + ko2];
      }
      #pragma unroll
      for (int mi = 0; mi < 4; ++mi)
        #pragma unroll
        for (int ni = 0; ni < 4; ++ni)
          acc[mi][ni] = MFMA_B16(af[mi], bf[ni], acc[mi][ni]);
    }
  }

  if (MODE == 0) {
    const int which = n0 / 768;           // uniform per block (128 | 768)
    const int nb = n0 % 768;
    #pragma unroll
    for (int mi = 0; mi < 4; ++mi)
      #pragma unroll
      for (int ni = 0; ni < 4; ++ni)
        #pragma unroll
        for (int r = 0; r < 4; ++r) {
          const int gm = m0 + mq + mi * 16 + rg * 4 + r;
          const int b  = gm / 2880;
          const int rr = gm - b * 2880;
          const int ng = nb + nq + ni * 16 + l15;
          const int h  = ng >> 6, d = ng & 63;
          const float c = acc[mi][ni][r];
          if (which == 0) {
            if (rr < 576)
              qbuf[((size_t)(b * 12 + h) * 576 + rr) * 64 + d] = f2bf(c * 0.125f);
          } else if (which == 1) {
            kbuf[((size_t)(b * 12 + h) * 2880 + rr) * 64 + d] = f2bf(c);
          } else {
            vbuf[((size_t)(b * 12 + h) * 2880 + rr) * 64 + d] = f2bf(c);
          }
        }
  } else {
    #pragma unroll
    for (int mi = 0; mi < 4; ++mi)
      #pragma unroll
      for (int ni = 0; ni < 4; ++ni)
        #pragma unroll
        for (int r = 0; r < 4; ++r) {
          const int gm = m0 + mq + mi * 16 + rg * 4 + r;
          const int gn = n0 + nq + ni * 16 + l15;
          const int b = gm / 576;
          const int q = gm - b * 576;
          fout[((size_t)b * 2880 + q) * 768 + gn] = acc[mi][ni][r] + bias[gn];
        }
  }
}

// ---------------- fused attention, round 5 ----------------
// block = (b, h, 16 q-rows), 256 threads (4 waves), ~19KB LDS -> 8 blocks/CU.
// Bijective XCD swizzle. 5 key-chunks of 576. Scores stored as exp(score)
// (exp is monotonic -> topk searches exp keys directly). Topk: branchless
// 16-round binary search, 2 rows interleaved. Selected keep exp, others -> 0.
// Dense PV MFMA per chunk accumulates in registers.
// LDS row permutation perm(q) = ((q&3)<<2)|(q>>2): score writes hit 4
// consecutive LDS rows -> <=2-way bank conflicts (free).
__global__ __launch_bounds__(256, 8) void attn_kernel(
    const u16* __restrict__ qbuf, const u16* __restrict__ kbuf,
    const u16* __restrict__ vtb, u16* __restrict__ aout)
{
  constexpr int PST = 584;                       // u16 stride (1168 B, 16B aligned)
  __shared__ __align__(16) u16 s_p[16 * PST];    // 18.7 KB exp(scores) / P
  __shared__ float s_denom[16];

  // XCD-bijective remap: 3456 = 8 XCDs * 432; 432 = 36 qt * 12 h (one batch/XCD)
  const int bid = blockIdx.x;
  const int L = (bid & 7) * 432 + (bid >> 3);
  const int qt = L % 36;
  const int h  = (L / 36) % 12;
  const int b  = L / 432;
  const int bh = b * 12 + h;
  const int q0 = qt * 16;
  const int tid = threadIdx.x, w = tid >> 6, lane = tid & 63;
  const int l15 = lane & 15, rg = lane >> 4;
  const int ko = rg * 8;

  // Q A-fragments for the block's 16 rows (2 K-halves)
  const u16* qp = qbuf + ((size_t)bh * 576 + q0) * 64;
  s16x8 aQ[2];
  aQ[0] = *(const s16x8*)&qp[l15 * 64 + ko];
  aQ[1] = *(const s16x8*)&qp[l15 * 64 + 32 + ko];

  const u16* kp = kbuf + (size_t)bh * 2880 * 64;
  const u16* vt = vtb + ((size_t)bh * 64 + w * 16 + l15) * 2880;
  const int prow = (((l15 & 3) << 2) | (l15 >> 2)) * PST;   // perm row for PV
  f32x4 zz = {0.f, 0.f, 0.f, 0.f};
  f32x4 accO = zz;

  // topk helpers -------------------------------------------------------
  auto writeback = [&](int q, int lrow, const unsigned* k, unsigned prefix) {
    unsigned long long eqm[9];
    int cnt_gt = 0;
    #pragma unroll
    for (int j = 0; j < 9; ++j) {
      unsigned long long ge = __ballot(k[j] >= prefix);
      unsigned long long gt = __ballot(k[j] >  prefix);
      eqm[j] = ge ^ gt;
      cnt_gt += __popcll(gt);
    }
    const int rem = 32 - cnt_gt;       // tie slots (lowest index wins)
    int run_eq = 0;
    float dsum = 0.f;
    #pragma unroll
    for (int j = 0; j < 9; ++j) {
      const bool isgt = k[j] > prefix;
      const bool iseq = k[j] == prefix;
      const bool sel = isgt || (iseq && (run_eq + lanes_below(eqm[j])) < rem);
      const u16 raw = (u16)(k[j] & 0x7FFFu);
      dsum += sel ? bf2f(raw) : 0.f;
      s_p[lrow + lane + 64 * j] = sel ? raw : (u16)0;
      run_eq += __popcll(eqm[j]);
    }
    #pragma unroll
    for (int off = 1; off < 64; off <<= 1) dsum += __shfl_xor(dsum, off);
    if (lane == 0) s_denom[q] += dsum;
  };

  auto topk2 = [&](int qA, int qB) {
    const int lrA = ((((qA & 3) << 2) | (qA >> 2))) * PST;
    const int lrB = ((((qB & 3) << 2) | (qB >> 2))) * PST;
    unsigned kA[9], kB[9];
    #pragma unroll
    for (int j = 0; j < 9; ++j) {
      kA[j] = (unsigned)s_p[lrA + lane + 64 * j] | 0x8000u;
      kB[j] = (unsigned)s_p[lrB + lane + 64 * j] | 0x8000u;
    }
    unsigned pA = 0, pB = 0;
    #pragma unroll
    for (int bit = 15; bit >= 0; --bit) {
      const unsigned cA = pA | (1u << bit), cB = pB | (1u << bit);
      int nA = 0, nB = 0;
      #pragma unroll
      for (int j = 0; j < 9; ++j) {
        nA += __popcll(__ballot(kA[j] >= cA));
        nB += __popcll(__ballot(kB[j] >= cB));
      }
      pA = (nA >= 32) ? cA : pA;       // wave-uniform -> s_cselect, branchless
      pB = (nB >= 32) ? cB : pB;
    }
    writeback(qA, lrA, kA, pA);
    writeback(qB, lrB, kB, pB);
  };
  // --------------------------------------------------------------------

  for (int c = 0; c < 5; ++c) {
    // ---- scores (stored as exp): wave w covers chunk-local keys [w*144, +144) ----
    #pragma unroll 3
    for (int t = 0; t < 9; ++t) {
      const int wk = w * 144 + t * 16;
      const u16* kr = kp + (size_t)(c * 576 + wk + l15) * 64 + ko;
      s16x8 kf0 = *(const s16x8*)&kr[0];
      s16x8 kf1 = *(const s16x8*)&kr[32];
      f32x4 a0 = zz;
      a0 = MFMA_B16(aQ[0], kf0, a0);
      a0 = MFMA_B16(aQ[1], kf1, a0);
      #pragma unroll
      for (int r = 0; r < 4; ++r)       // q-row rg*4+r -> LDS row r*4+rg
        s_p[(r * 4 + rg) * PST + wk + l15] = f2bf(__expf(a0[r]));
    }
    __syncthreads();

    if (c == 0) {
      // ---- denom over qa: wave w owns rows w*4..w*4+3 ----
      #pragma unroll
      for (int ri = 0; ri < 4; ++ri) {
        const int q = w * 4 + ri;
        const int lrow = (((q & 3) << 2) | (q >> 2)) * PST;
        float s = 0.f;
        #pragma unroll
        for (int j = 0; j < 9; ++j) s += bf2f(s_p[lrow + lane + 64 * j]);
        #pragma unroll
        for (int off = 1; off < 64; off <<= 1) s += __shfl_xor(s, off);
        if (lane == 0) s_denom[q] = s;
      }
    } else {
      // ---- top-32 (branchless, 2-row interleaved): wave w rows w*4..w*4+3 ----
      topk2(w * 4 + 0, w * 4 + 1);
      topk2(w * 4 + 2, w * 4 + 3);
      __syncthreads();   // P writeback visible before PV reads all rows
    }

    // ---- dense PV over this chunk: wave w owns output cols d = w*16..+15 ----
    #pragma unroll 3
    for (int k0 = 0; k0 < 576; k0 += 32) {
      s16x8 vf = *(const s16x8*)&vt[c * 576 + k0 + ko];
      s16x8 pa = *(const s16x8*)&s_p[prow + k0 + ko];
      accO = MFMA_B16(pa, vf, accO);
    }
    __syncthreads();     // PV done before next chunk overwrites s_p
  }

  // ---- epilogue: wave w owns cols d = w*16..w*16+15 ----
  const int d = w * 16 + l15;
  #pragma unroll
  for (int r = 0; r < 4; ++r) {
    const int row = rg * 4 + r;
    const float val = accO[r] / s_denom[row];
    aout[((size_t)(b * 576 + q0 + row)) * 768 + h * 64 + d] = f2bf(val);
  }
}

// ---------------- host launcher ----------------
extern "C" void kernel_launch(void* const* d_in, const int* in_sizes, int n_in,
                              void* d_out, int out_size, void* d_ws, size_t ws_size,
                              hipStream_t stream)
{
  const float* x      = (const float*)d_in[0];
  const float* qkv_w  = (const float*)d_in[1];
  const float* proj_w = (const float*)d_in[2];
  const float* proj_b = (const float*)d_in[3];
  float* out = (float*)d_out;

  char* ws = (char*)d_ws;
  size_t off = 0;
  auto alloc = [&](size_t bytes) -> void* {
    void* p = ws + off;
    off += (bytes + 255) & ~(size_t)255;
    return p;
  };
  u16* xb   = (u16*)alloc((size_t)23040 * 768 * 2);   // x bf16
  u16* wqb  = (u16*)alloc((size_t)2304 * 768 * 2);    // qkv_w bf16
  u16* wpb  = (u16*)alloc((size_t)768 * 768 * 2);     // proj_w bf16
  u16* qbuf = (u16*)alloc((size_t)96 * 576 * 64 * 2); // q (pre-scaled 1/8)
  u16* vtb  = (u16*)alloc((size_t)96 * 64 * 2880 * 2);// v^T, full 2880 keys
  u16* aout = (u16*)alloc((size_t)4608 * 768 * 2);    // attention output (B*hw, C)
  // k/v (70.8 MB) live inside d_out during the early phases; proj +
  // passthrough overwrite d_out only after attn has consumed them.
  u16* kbuf = (u16*)d_out;
  u16* vbuf = kbuf + (size_t)96 * 2880 * 64;

  cvt_kernel<<<17280, 256, 0, stream>>>(x, xb, 17694720 / 4);
  cvt_kernel<<<1728, 256, 0, stream>>>(qkv_w, wqb, 1769472 / 4);
  cvt_kernel<<<576, 256, 0, stream>>>(proj_w, wpb, 589824 / 4);
  gemm_nt<0><<<dim3(18, 180), 256, 0, stream>>>(xb, wqb, nullptr,
                                                qbuf, kbuf, vbuf, nullptr);
  transpose_v<<<dim3(45, 96), 256, 0, stream>>>(vbuf, vtb);
  attn_kernel<<<3456, 256, 0, stream>>>(qbuf, kbuf, vtb, aout);
  gemm_nt<1><<<dim3(6, 36), 256, 0, stream>>>(aout, wpb, proj_b,
                                              nullptr, nullptr, nullptr, out);
  copy_tail_kernel<<<13824, 256, 0, stream>>>(x, out);
}

// Round 6
// 493.484 us; speedup vs baseline: 1.1079x; 1.1079x over previous
//
#include <hip/hip_runtime.h>
#include <hip/hip_bf16.h>

// Attention_89335319756981 — MI355X bf16-MFMA implementation, round 6.
// B=8, N=2880 (hw=576 + T=4 frames of 576), C=768, H=12, hd=64, TOPK=32.
//
// Round-6 changes:
//  - attn: round-4 topk structure (no spills) + exp-domain keys (cheap
//    writeback: sel ? raw : 0). Identity LDS row mapping.
//  - gemm0: v-tiles transposed in-epilogue via LDS (32KB union with sA/sB);
//    vbuf + transpose_v kernel deleted.

using s16x8 = __attribute__((ext_vector_type(8))) short;
using f32x4 = __attribute__((ext_vector_type(4))) float;
typedef unsigned short u16;

#define MFMA_B16(A,B,C) __builtin_amdgcn_mfma_f32_16x16x32_bf16(A,B,C,0,0,0)

__device__ __forceinline__ u16 f2bf(float f) {
  unsigned u = __float_as_uint(f);
  u += 0x7FFFu + ((u >> 16) & 1u);          // RNE, no NaN inputs here
  return (u16)(u >> 16);
}
__device__ __forceinline__ float bf2f(u16 h) {
  return __uint_as_float(((unsigned)h) << 16);
}
__device__ __forceinline__ int lanes_below(unsigned long long m) {
  return __builtin_amdgcn_mbcnt_hi((unsigned)(m >> 32),
         __builtin_amdgcn_mbcnt_lo((unsigned)m, 0));
}
__device__ __forceinline__ void stage16(const u16* __restrict__ g, u16* l) {
  __builtin_amdgcn_global_load_lds(
      (const __attribute__((address_space(1))) unsigned int*)g,
      (__attribute__((address_space(3))) unsigned int*)l, 16, 0, 0);
}

// ---------------- f32 -> bf16 convert (4 elems/thread) ----------------
__global__ __launch_bounds__(256) void cvt_kernel(const float* __restrict__ src,
                                                  u16* __restrict__ dst, int n4) {
  int i = blockIdx.x * blockDim.x + threadIdx.x;
  if (i >= n4) return;
  float4 v = ((const float4*)src)[i];
  unsigned lo = (unsigned)f2bf(v.x) | ((unsigned)f2bf(v.y) << 16);
  unsigned hi = (unsigned)f2bf(v.z) | ((unsigned)f2bf(v.w) << 16);
  uint2 o; o.x = lo; o.y = hi;
  ((uint2*)dst)[i] = o;
}

// ---------------- passthrough copy: out[:,576:,:] = x[:,576:,:] ----------------
__global__ __launch_bounds__(256) void copy_tail_kernel(const float* __restrict__ x,
                                                        float* __restrict__ out) {
  int i = blockIdx.x * blockDim.x + threadIdx.x;   // float4 units
  int b = i / 442368;                              // 2304*768/4 per batch
  int off = i - b * 442368;
  size_t e = (size_t)b * 552960 + 110592 + off;    // (b*2880+576)*768/4 + off
  ((float4*)out)[e] = ((const float4*)x)[e];
}

// ---------------- NT GEMM, 128x128 tile, BK=64, global_load_lds ----------------
// C[m][n] = sum_k A[m][k]*Bw[n][k]. 4 waves, each 64x64 quadrant (4x4 frags).
// MODE 0: QKV epilogue (scatter q/k; v transposed in-block -> vtb).
// MODE 1: proj epilogue (f32 + bias -> out rows [0,576) per batch).
template<int MODE>
__global__ __launch_bounds__(256) void gemm_nt(
    const u16* __restrict__ A, const u16* __restrict__ Bw,
    const float* __restrict__ bias,
    u16* __restrict__ qbuf, u16* __restrict__ kbuf,
    u16* __restrict__ vtb, float* __restrict__ fout)
{
  __shared__ __align__(16) u16 smem[128 * 128];   // 32KB: sA|sB, reused for vT
  u16* sA = smem;
  u16* sB = smem + 128 * 64;
  const int n0 = blockIdx.x * 128;
  const int m0 = blockIdx.y * 128;
  if (MODE == 0 && n0 < 768) {
    // q columns only need rows rr<576; skip blocks fully inside rr>=576
    const int s = m0 % 2880;
    if (s >= 576 && s + 128 <= 2880) return;
  }
  const int tid = threadIdx.x;
  const int w = tid >> 6, lane = tid & 63;
  const int l15 = lane & 15, rg = lane >> 4;
  const int ko = rg * 8;
  const int mq = (w >> 1) * 64, nq = (w & 1) * 64;
  const int trow = tid >> 3, tcol = (tid & 7) * 8;   // staging map (lane-linear LDS)

  f32x4 z = {0.f, 0.f, 0.f, 0.f};
  f32x4 acc[4][4];
  #pragma unroll
  for (int i = 0; i < 4; ++i)
    #pragma unroll
    for (int j = 0; j < 4; ++j) acc[i][j] = z;

  for (int k0 = 0; k0 < 768; k0 += 64) {
    __syncthreads();
    #pragma unroll
    for (int i = 0; i < 4; ++i) {
      stage16(&A[(size_t)(m0 + trow + i * 32) * 768 + k0 + tcol],
              &sA[(trow + i * 32) * 64 + tcol]);
      stage16(&Bw[(size_t)(n0 + trow + i * 32) * 768 + k0 + tcol],
              &sB[(trow + i * 32) * 64 + tcol]);
    }
    __syncthreads();
    #pragma unroll
    for (int kk = 0; kk < 2; ++kk) {
      const int ko2 = kk * 32 + ko;
      s16x8 af[4], bf[4];
      #pragma unroll
      for (int i = 0; i < 4; ++i) {
        af[i] = *(const s16x8*)&sA[(mq + i * 16 + l15) * 64 + ko2];
        bf[i] = *(const s16x8*)&sB[(nq + i * 16 + l15) * 64 + ko2];
      }
      #pragma unroll
      for (int mi = 0; mi < 4; ++mi)
        #pragma unroll
        for (int ni = 0; ni < 4; ++ni)
          acc[mi][ni] = MFMA_B16(af[mi], bf[ni], acc[mi][ni]);
    }
  }

  if (MODE == 0) {
    const int which = n0 / 768;           // uniform per block (0=q, 1=k, 2=v)
    const int nb = n0 % 768;
    if (which == 2) {
      // ---- v: store tile to LDS bf16, then coalesced transposed write ----
      __syncthreads();
      #pragma unroll
      for (int mi = 0; mi < 4; ++mi)
        #pragma unroll
        for (int ni = 0; ni < 4; ++ni)
          #pragma unroll
          for (int r = 0; r < 4; ++r)
            smem[(mq + mi * 16 + rg * 4 + r) * 128 + nq + ni * 16 + l15] =
                f2bf(acc[mi][ni][r]);
      __syncthreads();
      // thread t: local col c (0..127), key half kh (0/1), 64 keys each.
      // 64-key runs never straddle a batch boundary (2880 % 64 == 0).
      const int c = tid & 127, kh = tid >> 7;
      const int gm0 = m0 + kh * 64;
      const int bb = gm0 / 2880, rr0 = gm0 - bb * 2880;
      const int ng = nb + c;
      const int hh = ng >> 6, dd = ng & 63;
      u16* dst = vtb + ((size_t)((bb * 12 + hh) * 64 + dd)) * 2880 + rr0;
      #pragma unroll
      for (int seg = 0; seg < 4; ++seg) {
        u16 tmp[16];
        #pragma unroll
        for (int i = 0; i < 16; ++i)
          tmp[i] = smem[(kh * 64 + seg * 16 + i) * 128 + c];
        *(int4*)&dst[seg * 16]     = *(const int4*)&tmp[0];
        *(int4*)&dst[seg * 16 + 8] = *(const int4*)&tmp[8];
      }
    } else {
      #pragma unroll
      for (int mi = 0; mi < 4; ++mi)
        #pragma unroll
        for (int ni = 0; ni < 4; ++ni)
          #pragma unroll
          for (int r = 0; r < 4; ++r) {
            const int gm = m0 + mq + mi * 16 + rg * 4 + r;
            const int b  = gm / 2880;
            const int rr = gm - b * 2880;
            const int ng = nb + nq + ni * 16 + l15;
            const int h  = ng >> 6, d = ng & 63;
            const float cc = acc[mi][ni][r];
            if (which == 0) {
              if (rr < 576)
                qbuf[((size_t)(b * 12 + h) * 576 + rr) * 64 + d] = f2bf(cc * 0.125f);
            } else {
              kbuf[((size_t)(b * 12 + h) * 2880 + rr) * 64 + d] = f2bf(cc);
            }
          }
    }
  } else {
    #pragma unroll
    for (int mi = 0; mi < 4; ++mi)
      #pragma unroll
      for (int ni = 0; ni < 4; ++ni)
        #pragma unroll
        for (int r = 0; r < 4; ++r) {
          const int gm = m0 + mq + mi * 16 + rg * 4 + r;
          const int gn = n0 + nq + ni * 16 + l15;
          const int b = gm / 576;
          const int q = gm - b * 576;
          fout[((size_t)b * 2880 + q) * 768 + gn] = acc[mi][ni][r] + bias[gn];
        }
  }
}

// ---------------- fused attention, round 6 ----------------
// block = (b, h, 16 q-rows), 256 threads (4 waves), ~19KB LDS -> 8 blocks/CU.
// Bijective XCD swizzle. 5 key-chunks of 576. Scores stored as exp(score)
// (monotonic -> topk searches exp keys). Per-row topk: ballot binary search
// with early exit (round-4 structure, no register blowup), writeback keeps
// exp for selected / 0 for others. Dense PV MFMA per chunk in registers.
__global__ __launch_bounds__(256, 8) void attn_kernel(
    const u16* __restrict__ qbuf, const u16* __restrict__ kbuf,
    const u16* __restrict__ vtb, u16* __restrict__ aout)
{
  constexpr int PST = 584;                       // u16 stride (1168 B, 16B aligned)
  __shared__ __align__(16) u16 s_p[16 * PST];    // 18.7 KB exp(scores) / P
  __shared__ float s_denom[16];

  // XCD-bijective remap: 3456 = 8 XCDs * 432; 432 = 36 qt * 12 h (one batch/XCD)
  const int bid = blockIdx.x;
  const int L = (bid & 7) * 432 + (bid >> 3);
  const int qt = L % 36;
  const int h  = (L / 36) % 12;
  const int b  = L / 432;
  const int bh = b * 12 + h;
  const int q0 = qt * 16;
  const int tid = threadIdx.x, w = tid >> 6, lane = tid & 63;
  const int l15 = lane & 15, rg = lane >> 4;
  const int ko = rg * 8;

  // Q A-fragments for the block's 16 rows (2 K-halves)
  const u16* qp = qbuf + ((size_t)bh * 576 + q0) * 64;
  s16x8 aQ[2];
  aQ[0] = *(const s16x8*)&qp[l15 * 64 + ko];
  aQ[1] = *(const s16x8*)&qp[l15 * 64 + 32 + ko];

  const u16* kp = kbuf + (size_t)bh * 2880 * 64;
  const u16* vt = vtb + ((size_t)bh * 64 + w * 16 + l15) * 2880;
  f32x4 zz = {0.f, 0.f, 0.f, 0.f};
  f32x4 accO = zz;

  for (int c = 0; c < 5; ++c) {
    // ---- scores (stored as exp): wave w covers chunk-local keys [w*144, +144) ----
    #pragma unroll 3
    for (int t = 0; t < 9; ++t) {
      const int wk = w * 144 + t * 16;
      const u16* kr = kp + (size_t)(c * 576 + wk + l15) * 64 + ko;
      s16x8 kf0 = *(const s16x8*)&kr[0];
      s16x8 kf1 = *(const s16x8*)&kr[32];
      f32x4 a0 = zz;
      a0 = MFMA_B16(aQ[0], kf0, a0);
      a0 = MFMA_B16(aQ[1], kf1, a0);
      #pragma unroll
      for (int r = 0; r < 4; ++r)
        s_p[(rg * 4 + r) * PST + wk + l15] = f2bf(__expf(a0[r]));
    }
    __syncthreads();

    if (c == 0) {
      // ---- denom over qa: wave w owns rows w*4..w*4+3 ----
      #pragma unroll
      for (int ri = 0; ri < 4; ++ri) {
        const int q = w * 4 + ri;
        float s = 0.f;
        #pragma unroll
        for (int j = 0; j < 9; ++j) s += bf2f(s_p[q * PST + lane + 64 * j]);
        #pragma unroll
        for (int off = 1; off < 64; off <<= 1) s += __shfl_xor(s, off);
        if (lane == 0) s_denom[q] = s;
      }
    } else {
      // ---- top-32 + zero-writeback: wave w owns rows w*4..w*4+3 ----
      for (int ri = 0; ri < 4; ++ri) {
        const int q = w * 4 + ri;
        unsigned key[9];
        #pragma unroll
        for (int j = 0; j < 9; ++j)
          key[j] = (unsigned)s_p[q * PST + lane + 64 * j] | 0x8000u;
        unsigned prefix = 0;
        for (int bit = 15; bit >= 0; --bit) {
          const unsigned cand = prefix | (1u << bit);
          int cnt = 0;
          #pragma unroll
          for (int j = 0; j < 9; ++j)
            cnt += __popcll(__ballot(key[j] >= cand));
          if (cnt >= 32) prefix = cand;
          if (cnt == 32) break;
        }
        unsigned long long eqm[9];
        int cnt_gt = 0;
        #pragma unroll
        for (int j = 0; j < 9; ++j) {
          cnt_gt += __popcll(__ballot(key[j] > prefix));
          eqm[j] = __ballot(key[j] == prefix);
        }
        const int rem = 32 - cnt_gt;     // tie slots (lowest index wins)
        int run_eq = 0;
        float dsum = 0.f;
        #pragma unroll
        for (int j = 0; j < 9; ++j) {
          const bool sel = (key[j] > prefix) ||
              (key[j] == prefix && run_eq + lanes_below(eqm[j]) < rem);
          const u16 raw = (u16)(key[j] & 0x7FFFu);
          dsum += sel ? bf2f(raw) : 0.f;
          s_p[q * PST + lane + 64 * j] = sel ? raw : (u16)0;
          run_eq += __popcll(eqm[j]);
        }
        #pragma unroll
        for (int off = 1; off < 64; off <<= 1) dsum += __shfl_xor(dsum, off);
        if (lane == 0) s_denom[q] += dsum;
      }
      __syncthreads();   // P writeback visible before PV reads all rows
    }

    // ---- dense PV over this chunk: wave w owns output cols d = w*16..+15 ----
    #pragma unroll 3
    for (int k0 = 0; k0 < 576; k0 += 32) {
      s16x8 vf = *(const s16x8*)&vt[c * 576 + k0 + ko];
      s16x8 pa = *(const s16x8*)&s_p[l15 * PST + k0 + ko];
      accO = MFMA_B16(pa, vf, accO);
    }
    __syncthreads();     // PV done before next chunk overwrites s_p
  }

  // ---- epilogue: wave w owns cols d = w*16..w*16+15 ----
  const int d = w * 16 + l15;
  #pragma unroll
  for (int r = 0; r < 4; ++r) {
    const int row = rg * 4 + r;
    const float val = accO[r] / s_denom[row];
    aout[((size_t)(b * 576 + q0 + row)) * 768 + h * 64 + d] = f2bf(val);
  }
}

// ---------------- host launcher ----------------
extern "C" void kernel_launch(void* const* d_in, const int* in_sizes, int n_in,
                              void* d_out, int out_size, void* d_ws, size_t ws_size,
                              hipStream_t stream)
{
  const float* x      = (const float*)d_in[0];
  const float* qkv_w  = (const float*)d_in[1];
  const float* proj_w = (const float*)d_in[2];
  const float* proj_b = (const float*)d_in[3];
  float* out = (float*)d_out;

  char* ws = (char*)d_ws;
  size_t off = 0;
  auto alloc = [&](size_t bytes) -> void* {
    void* p = ws + off;
    off += (bytes + 255) & ~(size_t)255;
    return p;
  };
  u16* xb   = (u16*)alloc((size_t)23040 * 768 * 2);   // x bf16
  u16* wqb  = (u16*)alloc((size_t)2304 * 768 * 2);    // qkv_w bf16
  u16* wpb  = (u16*)alloc((size_t)768 * 768 * 2);     // proj_w bf16
  u16* qbuf = (u16*)alloc((size_t)96 * 576 * 64 * 2); // q (pre-scaled 1/8)
  u16* vtb  = (u16*)alloc((size_t)96 * 64 * 2880 * 2);// v^T, full 2880 keys
  u16* aout = (u16*)alloc((size_t)4608 * 768 * 2);    // attention output (B*hw, C)
  // k (35.4 MB) lives inside d_out during the early phases; proj +
  // passthrough overwrite d_out only after attn has consumed it.
  u16* kbuf = (u16*)d_out;

  cvt_kernel<<<17280, 256, 0, stream>>>(x, xb, 17694720 / 4);
  cvt_kernel<<<1728, 256, 0, stream>>>(qkv_w, wqb, 1769472 / 4);
  cvt_kernel<<<576, 256, 0, stream>>>(proj_w, wpb, 589824 / 4);
  gemm_nt<0><<<dim3(18, 180), 256, 0, stream>>>(xb, wqb, nullptr,
                                                qbuf, kbuf, vtb, nullptr);
  attn_kernel<<<3456, 256, 0, stream>>>(qbuf, kbuf, vtb, aout);
  gemm_nt<1><<<dim3(6, 36), 256, 0, stream>>>(aout, wpb, proj_b,
                                              nullptr, nullptr, nullptr, out);
  copy_tail_kernel<<<13824, 256, 0, stream>>>(x, out);
}